// Round 1
// baseline (36.654 us; speedup 1.0000x reference)
//
#include <hip/hip_runtime.h>

// Problem constants (from reference): B=64, N=100000, G=2048, A=100.0
#define GRASP_A 100.0f

// Kernel 1: copy V_predict -> V_new region of d_out, vectorized float4.
// B*N*3 = 19,200,000 floats = 4,800,000 float4 — divisible by 4, aligned.
__global__ void copy_v_kernel(const float4* __restrict__ src,
                              float4* __restrict__ dst, int n4) {
    int i = blockIdx.x * blockDim.x + threadIdx.x;
    int stride = gridDim.x * blockDim.x;
    for (; i < n4; i += stride) {
        dst[i] = src[i];
    }
}

// Kernel 2: one thread per (b,g). Gather vertex + weight, compute constraint
// projection, overwrite the gathered vertex row in V_new (indices are unique
// per batch so a plain overwrite with v + delta is exact), write L_new.
__global__ void grasp_kernel(const float* __restrict__ V_predict,
                             const float* __restrict__ L,
                             const float* __restrict__ grasp_points,
                             const float* __restrict__ V_w,
                             const float* __restrict__ C_grasp_d,
                             const int*   __restrict__ C_grasp,
                             float* __restrict__ V_new,
                             float* __restrict__ L_new,
                             int B, int N, int G) {
    int t = blockIdx.x * blockDim.x + threadIdx.x;
    int total = B * G;
    if (t >= total) return;

    int b = t / G;               // G=2048 pow2-ish; compiler turns into shift if pow2
    int idx = C_grasp[t];        // particle index within batch b

    long vbase = ((long)b * N + idx) * 3;
    float vx = V_predict[vbase];
    float vy = V_predict[vbase + 1];
    float vz = V_predict[vbase + 2];

    long gbase = (long)t * 3;
    float nx = vx - grasp_points[gbase];
    float ny = vy - grasp_points[gbase + 1];
    float nz = vz - grasp_points[gbase + 2];

    float D  = sqrtf(nx * nx + ny * ny + nz * nz);
    float Cv = D - C_grasp_d[t];
    float Lv = L[t];
    float Sg = V_w[(long)b * N + idx];

    // S = (Sg==0) ? inf : Sg  ->  L_delta = (-C - A*L) / (S + A); inf -> 0
    float L_delta = (Sg == 0.0f) ? 0.0f
                                 : (-Cv - GRASP_A * Lv) / (Sg + GRASP_A);

    L_new[t] = Lv + L_delta;

    // delta = Sg * L_delta * Nv / D  (D>0 a.s. with random data; NaN matches ref if D==0)
    float scale = Sg * L_delta / D;
    V_new[vbase]     = vx + scale * nx;
    V_new[vbase + 1] = vy + scale * ny;
    V_new[vbase + 2] = vz + scale * nz;
}

extern "C" void kernel_launch(void* const* d_in, const int* in_sizes, int n_in,
                              void* d_out, int out_size, void* d_ws, size_t ws_size,
                              hipStream_t stream) {
    const int B = 64, N = 100000, G = 2048;

    const float* V_predict   = (const float*)d_in[0];  // [B,N,3]
    const float* L           = (const float*)d_in[1];  // [B,G,1]
    const float* grasp_pts   = (const float*)d_in[2];  // [B,G,3]
    const float* V_w         = (const float*)d_in[3];  // [B,N,1]
    const float* C_grasp_d   = (const float*)d_in[4];  // [B,G,1]
    const int*   C_grasp     = (const int*)d_in[5];    // [B,G]

    float* V_new = (float*)d_out;                      // [B,N,3] flat
    float* L_new = (float*)d_out + (long)B * N * 3;    // [B,G,1] flat

    // Kernel 1: full copy (must run every launch; graph replays don't re-poison,
    // and kernel 2 overwrites gathered rows afterwards -> deterministic).
    const int n4 = (B * N * 3) / 4;  // 4,800,000
    const int cpBlocks = 2048, cpThreads = 256;
    copy_v_kernel<<<cpBlocks, cpThreads, 0, stream>>>(
        (const float4*)V_predict, (float4*)V_new, n4);

    // Kernel 2: B*G = 131072 threads
    const int total = B * G;
    const int gThreads = 256;
    const int gBlocks = (total + gThreads - 1) / gThreads;
    grasp_kernel<<<gBlocks, gThreads, 0, stream>>>(
        V_predict, L, grasp_pts, V_w, C_grasp_d, C_grasp,
        V_new, L_new, B, N, G);
}